// Round 13
// baseline (314.711 us; speedup 1.0000x reference)
//
#include <hip/hip_runtime.h>
#include <hip/hip_bf16.h>
#include <stdint.h>

typedef __attribute__((ext_vector_type(8))) short short8;
typedef __attribute__((ext_vector_type(4))) float f32x4;
typedef __attribute__((ext_vector_type(4))) int i32x4;

#define B_ 2
#define T_ 2048
#define D_ 2048
#define N_ 16
#define KH_ 8
#define H_ 128
#define WINDOW_ 1024

// float -> bf16 bits, round-to-nearest-even
__device__ __forceinline__ uint16_t f2bf(float f) {
  union { float f; uint32_t u; } a; a.f = f;
  uint32_t u = a.u;
  return (uint16_t)((u + 0x7FFFu + ((u >> 16) & 1u)) >> 16);
}
__device__ __forceinline__ float bf2f(uint16_t u) {
  union { uint32_t u; float f; } a; a.u = (uint32_t)u << 16;
  return a.f;
}

// async global->LDS, 16B per lane; lds dest is wave-uniform base (HW adds lane*16)
__device__ __forceinline__ void gl_lds16(const void* g, void* l) {
  __builtin_amdgcn_global_load_lds((const __attribute__((address_space(1))) void*)g,
                                   (__attribute__((address_space(3))) void*)l, 16, 0, 0);
}

// ---------------- elementwise f32 -> bf16 ----------------
__global__ __launch_bounds__(256) void k_f2b4(const float* __restrict__ src,
                                              uint16_t* __restrict__ dst, long n) {
  long i = ((long)blockIdx.x * 256 + threadIdx.x) * 4;
  if (i >= n) return;
  float4 v = *(const float4*)(src + i);
  uint64_t p = (uint64_t)f2bf(v.x) | ((uint64_t)f2bf(v.y) << 16) |
               ((uint64_t)f2bf(v.z) << 32) | ((uint64_t)f2bf(v.w) << 48);
  *(uint64_t*)(dst + i) = p;
}

// ---------------- merged q/kv weight transpose ----------------
__global__ __launch_bounds__(256)
void k_prep_qkv(const float* __restrict__ w_q, const float* __restrict__ w_kv,
                uint16_t* __restrict__ wq_t, uint16_t* __restrict__ wkv_t) {
  __shared__ float tile[32][33];
  int z = blockIdx.z;
  const float* s;
  uint16_t* d;
  if (z < 16) {
    s = w_q + (long)z * D_ * H_;
    d = wq_t + (long)z * H_ * D_;
  } else if (z < 24) {
    s = w_kv + (long)(z - 16) * D_ * H_;
    d = wkv_t + (long)(z - 16) * H_ * D_;
  } else {
    s = w_kv + (long)KH_ * D_ * H_ + (long)(z - 24) * D_ * H_;
    d = wkv_t + (long)1024 * 2048 + (long)(z - 24) * H_ * D_;
  }
  int c0 = blockIdx.x * 32, r0 = blockIdx.y * 32;
  int x = threadIdx.x, y = threadIdx.y;
#pragma unroll
  for (int j = 0; j < 4; ++j)
    tile[y + j * 8][x] = s[(long)(r0 + y + j * 8) * H_ + (c0 + x)];
  __syncthreads();
#pragma unroll
  for (int j = 0; j < 4; ++j)
    d[(long)(c0 + y + j * 8) * D_ + (r0 + x)] = f2bf(tile[x][y + j * 8]);
}

// ---------------- generic transpose (w_o) ----------------
__global__ __launch_bounds__(256)
void k_transpose_f2b(const float* __restrict__ src, uint16_t* __restrict__ dst,
                     int R, int C, int nb1, long sbs1, long sbs2, long dbs,
                     long src_off, int srs) {
  __shared__ float tile[32][33];
  int z = blockIdx.z;
  int b1 = z % nb1, b2 = z / nb1;
  const float* s = src + src_off + (long)b1 * sbs1 + (long)b2 * sbs2;
  uint16_t* d = dst + (long)z * dbs;
  int c0 = blockIdx.x * 32, r0 = blockIdx.y * 32;
  int x = threadIdx.x, y = threadIdx.y;
#pragma unroll
  for (int j = 0; j < 4; ++j)
    tile[y + j * 8][x] = s[(long)(r0 + y + j * 8) * srs + (c0 + x)];
  __syncthreads();
#pragma unroll
  for (int j = 0; j < 4; ++j)
    d[(long)(c0 + y + j * 8) * R + (r0 + x)] = f2bf(tile[x][y + j * 8]);
}

// ---------------- V transpose with attention swizzle (bf16 in/out) ----------------
__global__ __launch_bounds__(256)
void k_transpose_v(const uint16_t* __restrict__ kvg, uint16_t* __restrict__ vbt) {
  __shared__ uint16_t tile[32][33];
  int z = blockIdx.z;  // b*KH + kh
  int kh = z % KH_, b = z / KH_;
  const uint16_t* s = kvg + (long)b * T_ * 2048 + 1024 + kh * H_;
  uint16_t* d = vbt + (long)z * H_ * T_;
  int h0 = blockIdx.x * 32, s0 = blockIdx.y * 32;
  int x = threadIdx.x, y = threadIdx.y;
#pragma unroll
  for (int j = 0; j < 4; ++j)
    tile[y + j * 8][x] = s[(long)(s0 + y + j * 8) * 2048 + (h0 + x)];
  __syncthreads();
#pragma unroll
  for (int j = 0; j < 4; ++j) {
    int h = h0 + y + j * 8;
    int si = s0 + x;
    int ss = (si & ~63) | ((((si >> 3) & 7) ^ (h & 7)) << 3) | (si & 7);
    d[(long)h * T_ + ss] = tile[x][y + j * 8];
  }
}

// ================= 256x256 8-phase GEMM, bf16 output ====
__global__ __launch_bounds__(512, 2)
void k_gemm8(const uint16_t* __restrict__ A, const uint16_t* __restrict__ Bt,
             uint16_t* __restrict__ C0, uint16_t* __restrict__ C1, int nbx, int splitc) {
  __shared__ __align__(16) uint16_t Ls[2][2][2][128 * 64];  // 128 KiB
  int tid = threadIdx.x, lane = tid & 63, w = tid >> 6;
  int wm = w >> 2, wn = w & 3;
  int fr = lane & 15, fgrp = lane >> 4;
  int bid = blockIdx.x;
  int k2 = bid >> 3;
  long by = (bid & 7) * 2 + k2 / nbx;   // XCD-chunked: each XCD owns 2 row-panels
  long bx = k2 % nbx;
  long row0 = by * 256, col0 = bx * 256;

  int trow = tid >> 3;
  int kse = (((tid & 7) * 16) ^ ((trow & 7) << 4)) >> 1;
  const uint16_t* aS[2] = { A + (row0 + trow) * 2048 + kse,
                            A + (row0 + 128 + trow) * 2048 + kse };
  const uint16_t* bS[2] = { Bt + (col0 + trow) * 2048 + kse,
                            Bt + (col0 + 128 + trow) * 2048 + kse };
  char* ldsbase = (char*)Ls + w * 1024;

  int kx[2] = { (fgrp * 16) ^ ((fr & 7) << 4), (64 + fgrp * 16) ^ ((fr & 7) << 4) };
  int aoffb = (wm * 64 + fr) * 128;
  int boffb = (wn * 32 + fr) * 128;
  const char* LA = (const char*)Ls;
  const char* LB = LA + 65536;

  f32x4 acc[2][2][4][2];
#pragma unroll
  for (int qm = 0; qm < 2; ++qm)
#pragma unroll
    for (int qn = 0; qn < 2; ++qn)
#pragma unroll
      for (int m = 0; m < 4; ++m)
#pragma unroll
        for (int n = 0; n < 2; ++n) acc[qm][qn][m][n] = (f32x4){0.f, 0.f, 0.f, 0.f};

  short8 RA[4][2];
  short8 RB[2][2][2];

#define STG(MAT, SLOT, HALF, KT) do {                                      \
    const uint16_t* _g = (MAT ? bS[HALF] : aS[HALF]) + (KT) * 64;          \
    char* _l = ldsbase + (MAT) * 65536 + (SLOT) * 32768 + (HALF) * 16384;  \
    gl_lds16(_g, _l);                                                      \
    gl_lds16(_g + 64 * 2048, _l + 8192);                                   \
  } while (0)

#define RDA(SLOT, QM) do {                                                             \
    _Pragma("unroll") for (int m = 0; m < 4; ++m) {                                    \
      RA[m][0] = *(const short8*)(LA + (SLOT)*32768 + (QM)*16384 + aoffb + m*2048 + kx[0]); \
      RA[m][1] = *(const short8*)(LA + (SLOT)*32768 + (QM)*16384 + aoffb + m*2048 + kx[1]); } \
  } while (0)

#define RDB(SLOT, QN) do {                                                             \
    _Pragma("unroll") for (int n = 0; n < 2; ++n) {                                    \
      RB[QN][n][0] = *(const short8*)(LB + (SLOT)*32768 + (QN)*16384 + boffb + n*2048 + kx[0]); \
      RB[QN][n][1] = *(const short8*)(LB + (SLOT)*32768 + (QN)*16384 + boffb + n*2048 + kx[1]); } \
  } while (0)

#define PHX(RDSTMT, STGSTMT, QM, QN, VM) do {                                         \
    RDSTMT;                                                                           \
    STGSTMT;                                                                          \
    __builtin_amdgcn_s_barrier();                                                     \
    asm volatile("s_waitcnt lgkmcnt(0)" ::: "memory");                                \
    __builtin_amdgcn_sched_barrier(0);                                                \
    __builtin_amdgcn_s_setprio(1);                                                    \
    _Pragma("unroll") for (int m = 0; m < 4; ++m)                                     \
      _Pragma("unroll") for (int n = 0; n < 2; ++n) {                                 \
        acc[QM][QN][m][n] = __builtin_amdgcn_mfma_f32_16x16x32_bf16(RA[m][0], RB[QN][n][0], acc[QM][QN][m][n], 0, 0, 0); \
        acc[QM][QN][m][n] = __builtin_amdgcn_mfma_f32_16x16x32_bf16(RA[m][1], RB[QN][n][1], acc[QM][QN][m][n], 0, 0, 0); } \
    __builtin_amdgcn_s_setprio(0);                                                    \
    if (VM) { asm volatile("s_waitcnt vmcnt(8)" ::: "memory");                        \
              __builtin_amdgcn_sched_barrier(0); }                                    \
    __builtin_amdgcn_s_barrier();                                                     \
    __builtin_amdgcn_sched_barrier(0);                                                \
  } while (0)

  STG(0, 0, 0, 0); STG(1, 0, 0, 0); STG(1, 0, 1, 0); STG(0, 0, 1, 0);
  STG(0, 1, 0, 1); STG(1, 1, 0, 1); STG(1, 1, 1, 1); STG(0, 1, 1, 1);
  asm volatile("s_waitcnt vmcnt(8)" ::: "memory");
  __builtin_amdgcn_sched_barrier(0);
  __builtin_amdgcn_s_barrier();

#pragma unroll 1
  for (int it = 0; it < 16; ++it) {
    int t2 = (2 * it + 2) & 31, t3 = (2 * it + 3) & 31;
    PHX({ RDA(0, 0); RDB(0, 0); }, {}, 0, 0, 0);
    PHX({ RDB(0, 1); }, { STG(0, 0, 0, t2); STG(1, 0, 0, t2); }, 0, 1, 0);
    PHX({ RDA(0, 1); }, { STG(1, 0, 1, t2); }, 1, 1, 0);
    PHX({}, { STG(0, 0, 1, t2); }, 1, 0, 1);
    PHX({ RDA(1, 0); RDB(1, 0); }, {}, 0, 0, 0);
    PHX({ RDB(1, 1); }, { STG(0, 1, 0, t3); STG(1, 1, 0, t3); }, 0, 1, 0);
    PHX({ RDA(1, 1); }, { STG(1, 1, 1, t3); }, 1, 1, 0);
    PHX({}, { STG(0, 1, 1, t3); }, 1, 0, 1);
  }
#undef PHX
#undef RDA
#undef RDB
#undef STG

  int og = fgrp * 4;
  bool hic = (col0 >= splitc);
  uint16_t* Cb = hic ? C1 : C0;
  long cb = col0 - (hic ? splitc : 0);
#pragma unroll
  for (int qm = 0; qm < 2; ++qm)
#pragma unroll
    for (int qn = 0; qn < 2; ++qn)
#pragma unroll
      for (int m = 0; m < 4; ++m)
#pragma unroll
        for (int n = 0; n < 2; ++n) {
          long r = row0 + qm * 128 + wm * 64 + m * 16 + og;
          long c = cb + qn * 128 + wn * 32 + n * 16 + fr;
          uint16_t* cp = Cb + r * 2048 + c;
#pragma unroll
          for (int i = 0; i < 4; ++i) cp[(long)i * 2048] = f2bf(acc[qm][qn][m][n][i]);
        }
}

// ================= 256x128-tile 4-phase GEMM (o-projection, fp32 out) ============
__global__ __launch_bounds__(512, 2)
void k_gemm8n(const uint16_t* __restrict__ A, const uint16_t* __restrict__ Bt,
              float* __restrict__ C, int nbx) {
  __shared__ __align__(16) uint16_t LsA[2][2][128 * 64];  // 64 KiB
  __shared__ __align__(16) uint16_t LsB[2][128 * 64];     // 32 KiB
  int tid = threadIdx.x, lane = tid & 63, w = tid >> 6;
  int wm = w >> 2, wn = w & 3;
  int fr = lane & 15, fgrp = lane >> 4;
  int bid = blockIdx.x;
  int k2 = bid >> 3;
  long by = (bid & 7) * 2 + k2 / nbx;
  long bx = k2 % nbx;
  long row0 = by * 256, col0 = bx * 128;

  int trow = tid >> 3;
  int kse = (((tid & 7) * 16) ^ ((trow & 7) << 4)) >> 1;
  const uint16_t* aS[2] = { A + (row0 + trow) * 2048 + kse,
                            A + (row0 + 128 + trow) * 2048 + kse };
  const uint16_t* bS = Bt + (col0 + trow) * 2048 + kse;
  char* ldsA_w = (char*)LsA + w * 1024;
  char* ldsB_w = (char*)LsB + w * 1024;

  int kx[2] = { (fgrp * 16) ^ ((fr & 7) << 4), (64 + fgrp * 16) ^ ((fr & 7) << 4) };
  int aoffb = (wm * 64 + fr) * 128;
  int boffb = (wn * 32 + fr) * 128;
  const char* LA = (const char*)LsA;
  const char* LB = (const char*)LsB;

  f32x4 acc[2][4][2];
#pragma unroll
  for (int qm = 0; qm < 2; ++qm)
#pragma unroll
    for (int m = 0; m < 4; ++m)
#pragma unroll
      for (int n = 0; n < 2; ++n) acc[qm][m][n] = (f32x4){0.f, 0.f, 0.f, 0.f};

#define STGA(SLOT, HALF, KT) do {                                \
    const uint16_t* _g = aS[HALF] + (KT) * 64;                   \
    char* _l = ldsA_w + (SLOT) * 32768 + (HALF) * 16384;         \
    gl_lds16(_g, _l);                                            \
    gl_lds16(_g + 64 * 2048, _l + 8192);                         \
  } while (0)
#define STGB(SLOT, KT) do {                                      \
    const uint16_t* _g = bS + (KT) * 64;                         \
    char* _l = ldsB_w + (SLOT) * 16384;                          \
    gl_lds16(_g, _l);                                            \
    gl_lds16(_g + 64 * 2048, _l + 8192);                         \
  } while (0)

#define PHN(SLOT, QM, STMT, VM) do {                                                  \
    short8 _a[4][2], _b[2][2];                                                        \
    _Pragma("unroll") for (int m = 0; m < 4; ++m) {                                   \
      _a[m][0] = *(const short8*)(LA + (SLOT)*32768 + (QM)*16384 + aoffb + m*2048 + kx[0]); \
      _a[m][1] = *(const short8*)(LA + (SLOT)*32768 + (QM)*16384 + aoffb + m*2048 + kx[1]); } \
    _Pragma("unroll") for (int n = 0; n < 2; ++n) {                                   \
      _b[n][0] = *(const short8*)(LB + (SLOT)*16384 + boffb + n*2048 + kx[0]);        \
      _b[n][1] = *(const short8*)(LB + (SLOT)*16384 + boffb + n*2048 + kx[1]); }      \
    STMT;                                                                             \
    __builtin_amdgcn_s_barrier();                                                     \
    asm volatile("s_waitcnt lgkmcnt(0)" ::: "memory");                                \
    __builtin_amdgcn_sched_barrier(0);                                                \
    __builtin_amdgcn_s_setprio(1);                                                    \
    _Pragma("unroll") for (int m = 0; m < 4; ++m)                                     \
      _Pragma("unroll") for (int n = 0; n < 2; ++n) {                                 \
        acc[QM][m][n] = __builtin_amdgcn_mfma_f32_16x16x32_bf16(_a[m][0], _b[n][0], acc[QM][m][n], 0, 0, 0); \
        acc[QM][m][n] = __builtin_amdgcn_mfma_f32_16x16x32_bf16(_a[m][1], _b[n][1], acc[QM][m][n], 0, 0, 0); } \
    __builtin_amdgcn_s_setprio(0);                                                    \
    if (VM) { asm volatile("s_waitcnt vmcnt(2)" ::: "memory");                        \
              __builtin_amdgcn_sched_barrier(0); }                                    \
    __builtin_amdgcn_s_barrier();                                                     \
    __builtin_amdgcn_sched_barrier(0);                                                \
  } while (0)

  STGA(0, 0, 0); STGA(0, 1, 0); STGB(0, 0); STGA(1, 0, 1);
  asm volatile("s_waitcnt vmcnt(2)" ::: "memory");
  __builtin_amdgcn_sched_barrier(0);
  __builtin_amdgcn_s_barrier();

#pragma unroll 1
  for (int it = 0; it < 16; ++it) {
    int t1 = 2 * it + 1, t2 = (2 * it + 2) & 31, t3 = (2 * it + 3) & 31;
    PHN(0, 0, { STGA(1, 1, t1); STGB(1, t1); }, 0);
    PHN(0, 1, STGA(0, 0, t2), 1);
    PHN(1, 0, { STGA(0, 1, t2); STGB(0, t2); }, 0);
    PHN(1, 1, STGA(1, 0, t3), 1);
  }
#undef PHN
#undef STGA
#undef STGB

  int og = fgrp * 4;
#pragma unroll
  for (int qm = 0; qm < 2; ++qm)
#pragma unroll
    for (int m = 0; m < 4; ++m)
#pragma unroll
      for (int n = 0; n < 2; ++n) {
        long r = row0 + qm * 128 + wm * 64 + m * 16 + og;
        long c = col0 + wn * 32 + n * 16 + fr;
        float* cp = C + r * 2048 + c;
#pragma unroll
        for (int i = 0; i < 4; ++i) cp[(long)i * 2048] = acc[qm][m][n][i];
      }
}

// ---------------- q post: RMSNorm + RoPE + Q_SCALE, bf16 -> bf16 ----------------
__global__ __launch_bounds__(256)
void k_qpost(const uint16_t* __restrict__ qg, const float* __restrict__ qs,
             uint16_t* __restrict__ qb) {
  int gw = blockIdx.x * 4 + (threadIdx.x >> 6);
  int lane = threadIdx.x & 63;
  int bt = gw / N_;
  int t = bt % T_;
  const uint16_t* src = qg + (long)gw * H_;
  float x1 = bf2f(src[lane]), x2 = bf2f(src[lane + 64]);
  float ssq = x1 * x1 + x2 * x2;
#pragma unroll
  for (int off = 1; off < 64; off <<= 1) ssq += __shfl_xor(ssq, off);
  float inv = rsqrtf(ssq * (1.0f / 128.0f) + 1e-6f);
  float n1 = x1 * inv * (1.0f + qs[lane]);
  float n2 = x2 * inv * (1.0f + qs[lane + 64]);
  float ts = powf(10000.0f, (float)lane * (2.0f / 128.0f));
  float ang = (float)t / ts;
  float sn, cs;
  sincosf(ang, &sn, &cs);
  const float QSC = 0.08838834764831845f;  // 128^-0.5
  uint16_t* dp = qb + (long)gw * H_;
  dp[lane] = f2bf((n1 * cs - n2 * sn) * QSC);
  dp[lane + 64] = f2bf((n2 * cs + n1 * sn) * QSC);
}

// ---------------- k post: RMSNorm + RoPE, bf16 in, (B,KH,T,H) pre-swizzled -------
__global__ __launch_bounds__(256)
void k_kpost(const uint16_t* __restrict__ kvg, const float* __restrict__ ks,
             uint16_t* __restrict__ kb) {
  int gw = blockIdx.x * 4 + (threadIdx.x >> 6);  // (b*T+t)*KH + kh
  int lane = threadIdx.x & 63;
  int kh = gw % KH_;
  int bt = gw / KH_;
  int t = bt % T_, b = bt / T_;
  const uint16_t* src = kvg + (long)bt * (KH_ * H_ * 2) + kh * H_;
  float x1 = bf2f(src[lane]), x2 = bf2f(src[lane + 64]);
  float ssq = x1 * x1 + x2 * x2;
#pragma unroll
  for (int off = 1; off < 64; off <<= 1) ssq += __shfl_xor(ssq, off);
  float inv = rsqrtf(ssq * (1.0f / 128.0f) + 1e-6f);
  float n1 = x1 * inv * (1.0f + ks[lane]);
  float n2 = x2 * inv * (1.0f + ks[lane + 64]);
  float ts = powf(10000.0f, (float)lane * (2.0f / 128.0f));
  float ang = (float)t / ts;
  float sn, cs;
  sincosf(ang, &sn, &cs);
  int sw = (t & 7) << 3;
  uint16_t* dp = kb + ((long)(b * KH_ + kh) * T_ + t) * H_;
  dp[lane ^ sw] = f2bf(n1 * cs - n2 * sn);
  dp[(lane + 64) ^ sw] = f2bf(n2 * cs + n1 * sn);
}

// ---------------- flash attention: single-buffer LDS + reg-staged prefetch (T14) --
// issue loads(t+1)->regs BEFORE compute(t); after barrier, vmcnt+ds_write regs->LDS.
// 40KB LDS => 4 blocks/CU; prefetch hides HBM/L2 latency under compute.
__global__ __launch_bounds__(256, 4)
void k_attn(const uint16_t* __restrict__ qb, const uint16_t* __restrict__ kb,
            const uint16_t* __restrict__ vbt, uint16_t* __restrict__ enc) {
  __shared__ uint16_t Ks[64 * 128];   // 16KB
  __shared__ uint16_t Vs[128 * 64];   // 16KB
  __shared__ uint16_t Pl[4][16 * 64]; // 8KB
  int tid = threadIdx.x, lane = tid & 63, w = tid >> 6;
  int nt = T_ / 64;
  int blk = blockIdx.x;
  int tq = nt - 1 - (blk >> 5);
  int bn = blk & 31;
  int n = bn % N_, b = bn / N_;
  int kh = n >> 1;  // G = 2
  int t0 = tq * 64;
  int tw = t0 + w * 16;
  int fr = lane & 15, fgrp = lane >> 4, fk = fgrp * 8;
  int sw3 = fr & 7;

  const uint16_t* qrow = qb + ((long)(b * T_ + tw + fr) * N_ + n) * H_;
  short8 aq[4];
#pragma unroll
  for (int kk = 0; kk < 4; ++kk) aq[kk] = *(const short8*)(qrow + kk * 32 + fk);

  float lrow[4];
  f32x4 o[8];
#pragma unroll
  for (int i = 0; i < 4; ++i) lrow[i] = 0.0f;
#pragma unroll
  for (int hf = 0; hf < 8; ++hf) o[hf] = (f32x4){0.f, 0.f, 0.f, 0.f};

  int s_begin = t0 - (WINDOW_ - 1);
  if (s_begin < 0) s_begin = 0;
  s_begin &= ~63;
  int s_endex = t0 + 64;
  int nloc = (s_endex - s_begin) >> 6;

  const uint16_t* kbase = kb + (long)(b * KH_ + kh) * T_ * H_;
  const uint16_t* vbase = vbt + (long)(b * KH_ + kh) * H_ * T_;
  int krow_st = tid >> 4, kcol_st = (tid & 15) * 8;
  int vrow_st = tid >> 3, vcol_st = (tid & 7) * 8;
  uint16_t* Pw = Pl[w];
  // per-thread LDS write targets (byte offsets match gl_lds16 semantics)
  char* wK = (char*)Ks + w * 1024 + lane * 16;
  char* wV = (char*)Vs + w * 1024 + lane * 16;

  i32x4 pk[4], pv[4];  // prefetch regs: 32 VGPRs

#define LOADKV(S0) do {                                                              \
    _Pragma("unroll") for (int j = 0; j < 4; ++j) {                                  \
      pk[j] = *(const i32x4*)(kbase + (long)((S0) + j * 16 + krow_st) * H_ + kcol_st); \
      pv[j] = *(const i32x4*)(vbase + (long)(j * 32 + vrow_st) * T_ + (S0) + vcol_st); \
    }                                                                                \
  } while (0)
#define WRITEKV() do {                                                               \
    _Pragma("unroll") for (int j = 0; j < 4; ++j) {                                  \
      *(i32x4*)(wK + j * 4096) = pk[j];                                              \
      *(i32x4*)(wV + j * 4096) = pv[j];                                              \
    }                                                                                \
  } while (0)

  // prologue: tile 0 -> regs -> LDS
  LOADKV(s_begin);
  WRITEKV();
  __syncthreads();

  for (int it = 0; it < nloc; ++it) {
    int s0 = s_begin + (it << 6);
    if (it + 1 < nloc) LOADKV(s0 + 64);  // prefetch next tile into regs

    if (!(s0 > tw + 15 || s0 + 63 < tw - (WINDOW_ - 1))) {
      // ---- S = Q K^T ----
      f32x4 sc[4];
#pragma unroll
      for (int kc = 0; kc < 4; ++kc) {
        f32x4 a = (f32x4){0.f, 0.f, 0.f, 0.f};
        const uint16_t* kr = Ks + (kc * 16 + fr) * 128;
#pragma unroll
        for (int kk = 0; kk < 4; ++kk) {
          short8 bk = *(const short8*)(kr + ((((kk << 2) | fgrp) ^ sw3) << 3));
          a = __builtin_amdgcn_mfma_f32_16x16x32_bf16(aq[kk], bk, a, 0, 0, 0);
        }
        sc[kc] = a;
      }

      bool full = (s0 + 63 <= tw) && (s0 >= tw + 16 - WINDOW_);
#define SMBODY(FULL)                                                              \
      _Pragma("unroll") for (int i = 0; i < 4; ++i) {                             \
        int r = fgrp * 4 + i;                                                     \
        int rsw = (r & 7) << 3;                                                   \
        int trowq = tw + r;                                                       \
        float ps = 0.f;                                                           \
        _Pragma("unroll") for (int kc = 0; kc < 4; ++kc) {                        \
          float v = sc[kc][i];                                                    \
          float u = v * v * 4.0e-4f;                                              \
          float t50 = v * fmaf(u, fmaf(u, fmaf(u, -0.053968254f, 0.13333334f),    \
                                       -0.33333334f), 1.0f);                      \
          float p = __expf(t50 - 20.0f);                                          \
          if (!(FULL)) {                                                          \
            int s = s0 + kc * 16 + fr;                                            \
            bool ok = (s <= trowq) && (s > trowq - WINDOW_);                      \
            p = ok ? p : 0.0f;                                                    \
          }                                                                       \
          ps += p;                                                                \
          *(__hip_bfloat16*)(Pw + r * 64 + ((kc * 16 + fr) ^ rsw)) =              \
              __float2bfloat16(p);                                                \
        }                                                                         \
        lrow[i] += ps;                                                            \
      }
      if (full) { SMBODY(true) } else { SMBODY(false) }
#undef SMBODY

      // ---- O += P V ----
      short8 pa0 = *(const short8*)(Pw + fr * 64 + ((fgrp ^ sw3) << 3));
      short8 pa1 = *(const short8*)(Pw + fr * 64 + (((4 | fgrp) ^ sw3) << 3));
#pragma unroll
      for (int hf = 0; hf < 8; ++hf) {
        const uint16_t* vr = Vs + (hf * 16 + fr) * 64;
        short8 bv0 = *(const short8*)(vr + ((fgrp ^ sw3) << 3));
        short8 bv1 = *(const short8*)(vr + (((4 | fgrp) ^ sw3) << 3));
        o[hf] = __builtin_amdgcn_mfma_f32_16x16x32_bf16(pa0, bv0, o[hf], 0, 0, 0);
        o[hf] = __builtin_amdgcn_mfma_f32_16x16x32_bf16(pa1, bv1, o[hf], 0, 0, 0);
      }
    }
    __syncthreads();  // all waves done reading LDS tile t
    if (it + 1 < nloc) {
      WRITEKV();      // compiler inserts vmcnt before first use of pk/pv
      __syncthreads();  // writes visible before next compute (lgkm drain only)
    }
  }
#undef LOADKV
#undef WRITEKV

#pragma unroll
  for (int i = 0; i < 4; ++i) {
#pragma unroll
    for (int off = 1; off < 16; off <<= 1) lrow[i] += __shfl_xor(lrow[i], off);
    lrow[i] = 1.0f / lrow[i];
  }
#pragma unroll
  for (int hf = 0; hf < 8; ++hf)
#pragma unroll
    for (int i = 0; i < 4; ++i) {
      int t = tw + fgrp * 4 + i;
      float val = o[hf][i] * lrow[i];
      enc[((long)(b * T_ + t) * N_ + n) * H_ + hf * 16 + fr] = f2bf(val);
    }
}

// ---------------- host side ----------------
extern "C" void kernel_launch(void* const* d_in, const int* in_sizes, int n_in,
                              void* d_out, int out_size, void* d_ws, size_t ws_size,
                              hipStream_t stream) {
  const float* x = (const float*)d_in[0];
  const float* w_q = (const float*)d_in[1];
  const float* w_kv = (const float*)d_in[2];
  const float* w_o = (const float*)d_in[3];
  const float* qns = (const float*)d_in[4];
  const float* kns = (const float*)d_in[5];
  float* out = (float*)d_out;

  uint16_t* ws = (uint16_t*)d_ws;
  uint16_t* xb    = ws;                    // 8388608  : x bf16 (B*T, D)
  uint16_t* wq_t  = xb    + 8388608;       // 4194304  : (N*H, D)
  uint16_t* wkv_t = wq_t  + 4194304;       // 4194304  : contiguous after wq_t -> fused B panel
  uint16_t* wo_t  = wkv_t + 4194304;       // 4194304  : (D, N*H)
  uint16_t* qb    = wo_t  + 4194304;       // 8388608  : (B,T,N,H)
  uint16_t* kb    = qb    + 8388608;       // 4194304  : (B,KH,T,H) pre-swizzled
  uint16_t* vbt   = kb    + 4194304;       // 4194304  : (B,KH,H,T) pre-swizzled
  uint16_t* enc   = vbt   + 4194304;       // 8388608  : (B,T,N,H)
  uint16_t* qg_b  = enc   + 8388608;       // 8388608  : q gemm out bf16 (B*T, N*H)
  uint16_t* kvg_b = qg_b  + 8388608;       // 8388608  : kv gemm out bf16 (B*T, 2*KH*H)
  if (ws_size < (size_t)125829120) return;

  dim3 tb(32, 8);
  k_f2b4<<<8192, 256, 0, stream>>>(x, xb, 8388608);
  k_prep_qkv<<<dim3(4, 64, 32), tb, 0, stream>>>(w_q, w_kv, wq_t, wkv_t);
  k_transpose_f2b<<<dim3(64, 64, 1), tb, 0, stream>>>(w_o, wo_t, 2048, 2048, 1,
      0, 0, 0, 0, 2048);
  // fused q+kv projection, bf16 out: cols<2048 -> qg_b, else kvg_b
  k_gemm8<<<256, 512, 0, stream>>>(xb, wq_t, qg_b, kvg_b, 16, 2048);
  k_qpost<<<(B_ * T_ * N_) / 4, 256, 0, stream>>>(qg_b, qns, qb);
  k_kpost<<<(B_ * T_ * KH_) / 4, 256, 0, stream>>>(kvg_b, kns, kb);
  k_transpose_v<<<dim3(4, 64, 16), tb, 0, stream>>>(kvg_b, vbt);
  k_attn<<<B_ * N_ * (T_ / 64), 256, 0, stream>>>(qb, kb, vbt, enc);
  // output projection: 256x128 tiles -> 256 blocks (full chip)
  k_gemm8n<<<256, 512, 0, stream>>>(enc, wo_t, out, 16);
}

// Round 15
// 222.944 us; speedup vs baseline: 1.4116x; 1.4116x over previous
//
#include <hip/hip_runtime.h>
#include <hip/hip_bf16.h>
#include <stdint.h>

typedef __attribute__((ext_vector_type(8))) short short8;
typedef __attribute__((ext_vector_type(4))) float f32x4;

#define B_ 2
#define T_ 2048
#define D_ 2048
#define N_ 16
#define KH_ 8
#define H_ 128
#define WINDOW_ 1024

// float -> bf16 bits, round-to-nearest-even
__device__ __forceinline__ uint16_t f2bf(float f) {
  union { float f; uint32_t u; } a; a.f = f;
  uint32_t u = a.u;
  return (uint16_t)((u + 0x7FFFu + ((u >> 16) & 1u)) >> 16);
}
__device__ __forceinline__ float bf2f(uint16_t u) {
  union { uint32_t u; float f; } a; a.u = (uint32_t)u << 16;
  return a.f;
}

// async global->LDS, 16B per lane; lds dest is wave-uniform base (HW adds lane*16)
__device__ __forceinline__ void gl_lds16(const void* g, void* l) {
  __builtin_amdgcn_global_load_lds((const __attribute__((address_space(1))) void*)g,
                                   (__attribute__((address_space(3))) void*)l, 16, 0, 0);
}

// ---------------- elementwise f32 -> bf16 ----------------
__global__ __launch_bounds__(256) void k_f2b4(const float* __restrict__ src,
                                              uint16_t* __restrict__ dst, long n) {
  long i = ((long)blockIdx.x * 256 + threadIdx.x) * 4;
  if (i >= n) return;
  float4 v = *(const float4*)(src + i);
  uint64_t p = (uint64_t)f2bf(v.x) | ((uint64_t)f2bf(v.y) << 16) |
               ((uint64_t)f2bf(v.z) << 32) | ((uint64_t)f2bf(v.w) << 48);
  *(uint64_t*)(dst + i) = p;
}

// ---------------- merged q/kv weight transpose ----------------
__global__ __launch_bounds__(256)
void k_prep_qkv(const float* __restrict__ w_q, const float* __restrict__ w_kv,
                uint16_t* __restrict__ wq_t, uint16_t* __restrict__ wkv_t) {
  __shared__ float tile[32][33];
  int z = blockIdx.z;
  const float* s;
  uint16_t* d;
  if (z < 16) {
    s = w_q + (long)z * D_ * H_;
    d = wq_t + (long)z * H_ * D_;
  } else if (z < 24) {
    s = w_kv + (long)(z - 16) * D_ * H_;
    d = wkv_t + (long)(z - 16) * H_ * D_;
  } else {
    s = w_kv + (long)KH_ * D_ * H_ + (long)(z - 24) * D_ * H_;
    d = wkv_t + (long)1024 * 2048 + (long)(z - 24) * H_ * D_;
  }
  int c0 = blockIdx.x * 32, r0 = blockIdx.y * 32;
  int x = threadIdx.x, y = threadIdx.y;
#pragma unroll
  for (int j = 0; j < 4; ++j)
    tile[y + j * 8][x] = s[(long)(r0 + y + j * 8) * H_ + (c0 + x)];
  __syncthreads();
#pragma unroll
  for (int j = 0; j < 4; ++j)
    d[(long)(c0 + y + j * 8) * D_ + (r0 + x)] = f2bf(tile[x][y + j * 8]);
}

// ---------------- generic transpose (w_o) ----------------
__global__ __launch_bounds__(256)
void k_transpose_f2b(const float* __restrict__ src, uint16_t* __restrict__ dst,
                     int R, int C, int nb1, long sbs1, long sbs2, long dbs,
                     long src_off, int srs) {
  __shared__ float tile[32][33];
  int z = blockIdx.z;
  int b1 = z % nb1, b2 = z / nb1;
  const float* s = src + src_off + (long)b1 * sbs1 + (long)b2 * sbs2;
  uint16_t* d = dst + (long)z * dbs;
  int c0 = blockIdx.x * 32, r0 = blockIdx.y * 32;
  int x = threadIdx.x, y = threadIdx.y;
#pragma unroll
  for (int j = 0; j < 4; ++j)
    tile[y + j * 8][x] = s[(long)(r0 + y + j * 8) * srs + (c0 + x)];
  __syncthreads();
#pragma unroll
  for (int j = 0; j < 4; ++j)
    d[(long)(c0 + y + j * 8) * R + (r0 + x)] = f2bf(tile[x][y + j * 8]);
}

// ---------------- V transpose with attention swizzle (bf16 in/out) ----------------
__global__ __launch_bounds__(256)
void k_transpose_v(const uint16_t* __restrict__ kvg, uint16_t* __restrict__ vbt) {
  __shared__ uint16_t tile[32][33];
  int z = blockIdx.z;  // b*KH + kh
  int kh = z % KH_, b = z / KH_;
  const uint16_t* s = kvg + (long)b * T_ * 2048 + 1024 + kh * H_;
  uint16_t* d = vbt + (long)z * H_ * T_;
  int h0 = blockIdx.x * 32, s0 = blockIdx.y * 32;
  int x = threadIdx.x, y = threadIdx.y;
#pragma unroll
  for (int j = 0; j < 4; ++j)
    tile[y + j * 8][x] = s[(long)(s0 + y + j * 8) * 2048 + (h0 + x)];
  __syncthreads();
#pragma unroll
  for (int j = 0; j < 4; ++j) {
    int h = h0 + y + j * 8;
    int si = s0 + x;
    int ss = (si & ~63) | ((((si >> 3) & 7) ^ (h & 7)) << 3) | (si & 7);
    d[(long)h * T_ + ss] = tile[x][y + j * 8];
  }
}

// ================= 256x256 8-phase GEMM, bf16 output ====
__global__ __launch_bounds__(512, 2)
void k_gemm8(const uint16_t* __restrict__ A, const uint16_t* __restrict__ Bt,
             uint16_t* __restrict__ C0, uint16_t* __restrict__ C1, int nbx, int splitc) {
  __shared__ __align__(16) uint16_t Ls[2][2][2][128 * 64];  // 128 KiB
  int tid = threadIdx.x, lane = tid & 63, w = tid >> 6;
  int wm = w >> 2, wn = w & 3;
  int fr = lane & 15, fgrp = lane >> 4;
  int bid = blockIdx.x;
  int k2 = bid >> 3;
  long by = (bid & 7) * 2 + k2 / nbx;   // XCD-chunked: each XCD owns 2 row-panels
  long bx = k2 % nbx;
  long row0 = by * 256, col0 = bx * 256;

  int trow = tid >> 3;
  int kse = (((tid & 7) * 16) ^ ((trow & 7) << 4)) >> 1;
  const uint16_t* aS[2] = { A + (row0 + trow) * 2048 + kse,
                            A + (row0 + 128 + trow) * 2048 + kse };
  const uint16_t* bS[2] = { Bt + (col0 + trow) * 2048 + kse,
                            Bt + (col0 + 128 + trow) * 2048 + kse };
  char* ldsbase = (char*)Ls + w * 1024;

  int kx[2] = { (fgrp * 16) ^ ((fr & 7) << 4), (64 + fgrp * 16) ^ ((fr & 7) << 4) };
  int aoffb = (wm * 64 + fr) * 128;
  int boffb = (wn * 32 + fr) * 128;
  const char* LA = (const char*)Ls;
  const char* LB = LA + 65536;

  f32x4 acc[2][2][4][2];
#pragma unroll
  for (int qm = 0; qm < 2; ++qm)
#pragma unroll
    for (int qn = 0; qn < 2; ++qn)
#pragma unroll
      for (int m = 0; m < 4; ++m)
#pragma unroll
        for (int n = 0; n < 2; ++n) acc[qm][qn][m][n] = (f32x4){0.f, 0.f, 0.f, 0.f};

  short8 RA[4][2];
  short8 RB[2][2][2];

#define STG(MAT, SLOT, HALF, KT) do {                                      \
    const uint16_t* _g = (MAT ? bS[HALF] : aS[HALF]) + (KT) * 64;          \
    char* _l = ldsbase + (MAT) * 65536 + (SLOT) * 32768 + (HALF) * 16384;  \
    gl_lds16(_g, _l);                                                      \
    gl_lds16(_g + 64 * 2048, _l + 8192);                                   \
  } while (0)

#define RDA(SLOT, QM) do {                                                             \
    _Pragma("unroll") for (int m = 0; m < 4; ++m) {                                    \
      RA[m][0] = *(const short8*)(LA + (SLOT)*32768 + (QM)*16384 + aoffb + m*2048 + kx[0]); \
      RA[m][1] = *(const short8*)(LA + (SLOT)*32768 + (QM)*16384 + aoffb + m*2048 + kx[1]); } \
  } while (0)

#define RDB(SLOT, QN) do {                                                             \
    _Pragma("unroll") for (int n = 0; n < 2; ++n) {                                    \
      RB[QN][n][0] = *(const short8*)(LB + (SLOT)*32768 + (QN)*16384 + boffb + n*2048 + kx[0]); \
      RB[QN][n][1] = *(const short8*)(LB + (SLOT)*32768 + (QN)*16384 + boffb + n*2048 + kx[1]); } \
  } while (0)

#define PHX(RDSTMT, STGSTMT, QM, QN, VM) do {                                         \
    RDSTMT;                                                                           \
    STGSTMT;                                                                          \
    __builtin_amdgcn_s_barrier();                                                     \
    asm volatile("s_waitcnt lgkmcnt(0)" ::: "memory");                                \
    __builtin_amdgcn_sched_barrier(0);                                                \
    __builtin_amdgcn_s_setprio(1);                                                    \
    _Pragma("unroll") for (int m = 0; m < 4; ++m)                                     \
      _Pragma("unroll") for (int n = 0; n < 2; ++n) {                                 \
        acc[QM][QN][m][n] = __builtin_amdgcn_mfma_f32_16x16x32_bf16(RA[m][0], RB[QN][n][0], acc[QM][QN][m][n], 0, 0, 0); \
        acc[QM][QN][m][n] = __builtin_amdgcn_mfma_f32_16x16x32_bf16(RA[m][1], RB[QN][n][1], acc[QM][QN][m][n], 0, 0, 0); } \
    __builtin_amdgcn_s_setprio(0);                                                    \
    if (VM) { asm volatile("s_waitcnt vmcnt(8)" ::: "memory");                        \
              __builtin_amdgcn_sched_barrier(0); }                                    \
    __builtin_amdgcn_s_barrier();                                                     \
    __builtin_amdgcn_sched_barrier(0);                                                \
  } while (0)

  STG(0, 0, 0, 0); STG(1, 0, 0, 0); STG(1, 0, 1, 0); STG(0, 0, 1, 0);
  STG(0, 1, 0, 1); STG(1, 1, 0, 1); STG(1, 1, 1, 1); STG(0, 1, 1, 1);
  asm volatile("s_waitcnt vmcnt(8)" ::: "memory");
  __builtin_amdgcn_sched_barrier(0);
  __builtin_amdgcn_s_barrier();

#pragma unroll 1
  for (int it = 0; it < 16; ++it) {
    int t2 = (2 * it + 2) & 31, t3 = (2 * it + 3) & 31;
    PHX({ RDA(0, 0); RDB(0, 0); }, {}, 0, 0, 0);
    PHX({ RDB(0, 1); }, { STG(0, 0, 0, t2); STG(1, 0, 0, t2); }, 0, 1, 0);
    PHX({ RDA(0, 1); }, { STG(1, 0, 1, t2); }, 1, 1, 0);
    PHX({}, { STG(0, 0, 1, t2); }, 1, 0, 1);
    PHX({ RDA(1, 0); RDB(1, 0); }, {}, 0, 0, 0);
    PHX({ RDB(1, 1); }, { STG(0, 1, 0, t3); STG(1, 1, 0, t3); }, 0, 1, 0);
    PHX({ RDA(1, 1); }, { STG(1, 1, 1, t3); }, 1, 1, 0);
    PHX({}, { STG(0, 1, 1, t3); }, 1, 0, 1);
  }
#undef PHX
#undef RDA
#undef RDB
#undef STG

  int og = fgrp * 4;
  bool hic = (col0 >= splitc);
  uint16_t* Cb = hic ? C1 : C0;
  long cb = col0 - (hic ? splitc : 0);
#pragma unroll
  for (int qm = 0; qm < 2; ++qm)
#pragma unroll
    for (int qn = 0; qn < 2; ++qn)
#pragma unroll
      for (int m = 0; m < 4; ++m)
#pragma unroll
        for (int n = 0; n < 2; ++n) {
          long r = row0 + qm * 128 + wm * 64 + m * 16 + og;
          long c = cb + qn * 128 + wn * 32 + n * 16 + fr;
          uint16_t* cp = Cb + r * 2048 + c;
#pragma unroll
          for (int i = 0; i < 4; ++i) cp[(long)i * 2048] = f2bf(acc[qm][qn][m][n][i]);
        }
}

// ================= 256x128-tile 4-phase GEMM (o-projection, fp32 out) ============
__global__ __launch_bounds__(512, 2)
void k_gemm8n(const uint16_t* __restrict__ A, const uint16_t* __restrict__ Bt,
              float* __restrict__ C, int nbx) {
  __shared__ __align__(16) uint16_t LsA[2][2][128 * 64];  // 64 KiB
  __shared__ __align__(16) uint16_t LsB[2][128 * 64];     // 32 KiB
  int tid = threadIdx.x, lane = tid & 63, w = tid >> 6;
  int wm = w >> 2, wn = w & 3;
  int fr = lane & 15, fgrp = lane >> 4;
  int bid = blockIdx.x;
  int k2 = bid >> 3;
  long by = (bid & 7) * 2 + k2 / nbx;
  long bx = k2 % nbx;
  long row0 = by * 256, col0 = bx * 128;

  int trow = tid >> 3;
  int kse = (((tid & 7) * 16) ^ ((trow & 7) << 4)) >> 1;
  const uint16_t* aS[2] = { A + (row0 + trow) * 2048 + kse,
                            A + (row0 + 128 + trow) * 2048 + kse };
  const uint16_t* bS = Bt + (col0 + trow) * 2048 + kse;
  char* ldsA_w = (char*)LsA + w * 1024;
  char* ldsB_w = (char*)LsB + w * 1024;

  int kx[2] = { (fgrp * 16) ^ ((fr & 7) << 4), (64 + fgrp * 16) ^ ((fr & 7) << 4) };
  int aoffb = (wm * 64 + fr) * 128;
  int boffb = (wn * 32 + fr) * 128;
  const char* LA = (const char*)LsA;
  const char* LB = (const char*)LsB;

  f32x4 acc[2][4][2];
#pragma unroll
  for (int qm = 0; qm < 2; ++qm)
#pragma unroll
    for (int m = 0; m < 4; ++m)
#pragma unroll
      for (int n = 0; n < 2; ++n) acc[qm][m][n] = (f32x4){0.f, 0.f, 0.f, 0.f};

#define STGA(SLOT, HALF, KT) do {                                \
    const uint16_t* _g = aS[HALF] + (KT) * 64;                   \
    char* _l = ldsA_w + (SLOT) * 32768 + (HALF) * 16384;         \
    gl_lds16(_g, _l);                                            \
    gl_lds16(_g + 64 * 2048, _l + 8192);                         \
  } while (0)
#define STGB(SLOT, KT) do {                                      \
    const uint16_t* _g = bS + (KT) * 64;                         \
    char* _l = ldsB_w + (SLOT) * 16384;                          \
    gl_lds16(_g, _l);                                            \
    gl_lds16(_g + 64 * 2048, _l + 8192);                         \
  } while (0)

#define PHN(SLOT, QM, STMT, VM) do {                                                  \
    short8 _a[4][2], _b[2][2];                                                        \
    _Pragma("unroll") for (int m = 0; m < 4; ++m) {                                   \
      _a[m][0] = *(const short8*)(LA + (SLOT)*32768 + (QM)*16384 + aoffb + m*2048 + kx[0]); \
      _a[m][1] = *(const short8*)(LA + (SLOT)*32768 + (QM)*16384 + aoffb + m*2048 + kx[1]); } \
    _Pragma("unroll") for (int n = 0; n < 2; ++n) {                                   \
      _b[n][0] = *(const short8*)(LB + (SLOT)*16384 + boffb + n*2048 + kx[0]);        \
      _b[n][1] = *(const short8*)(LB + (SLOT)*16384 + boffb + n*2048 + kx[1]); }      \
    STMT;                                                                             \
    __builtin_amdgcn_s_barrier();                                                     \
    asm volatile("s_waitcnt lgkmcnt(0)" ::: "memory");                                \
    __builtin_amdgcn_sched_barrier(0);                                                \
    __builtin_amdgcn_s_setprio(1);                                                    \
    _Pragma("unroll") for (int m = 0; m < 4; ++m)                                     \
      _Pragma("unroll") for (int n = 0; n < 2; ++n) {                                 \
        acc[QM][m][n] = __builtin_amdgcn_mfma_f32_16x16x32_bf16(_a[m][0], _b[n][0], acc[QM][m][n], 0, 0, 0); \
        acc[QM][m][n] = __builtin_amdgcn_mfma_f32_16x16x32_bf16(_a[m][1], _b[n][1], acc[QM][m][n], 0, 0, 0); } \
    __builtin_amdgcn_s_setprio(0);                                                    \
    if (VM) { asm volatile("s_waitcnt vmcnt(2)" ::: "memory");                        \
              __builtin_amdgcn_sched_barrier(0); }                                    \
    __builtin_amdgcn_s_barrier();                                                     \
    __builtin_amdgcn_sched_barrier(0);                                                \
  } while (0)

  STGA(0, 0, 0); STGA(0, 1, 0); STGB(0, 0); STGA(1, 0, 1);
  asm volatile("s_waitcnt vmcnt(2)" ::: "memory");
  __builtin_amdgcn_sched_barrier(0);
  __builtin_amdgcn_s_barrier();

#pragma unroll 1
  for (int it = 0; it < 16; ++it) {
    int t1 = 2 * it + 1, t2 = (2 * it + 2) & 31, t3 = (2 * it + 3) & 31;
    PHN(0, 0, { STGA(1, 1, t1); STGB(1, t1); }, 0);
    PHN(0, 1, STGA(0, 0, t2), 1);
    PHN(1, 0, { STGA(0, 1, t2); STGB(0, t2); }, 0);
    PHN(1, 1, STGA(1, 0, t3), 1);
  }
#undef PHN
#undef STGA
#undef STGB

  int og = fgrp * 4;
#pragma unroll
  for (int qm = 0; qm < 2; ++qm)
#pragma unroll
    for (int m = 0; m < 4; ++m)
#pragma unroll
      for (int n = 0; n < 2; ++n) {
        long r = row0 + qm * 128 + wm * 64 + m * 16 + og;
        long c = col0 + wn * 32 + n * 16 + fr;
        float* cp = C + r * 2048 + c;
#pragma unroll
        for (int i = 0; i < 4; ++i) cp[(long)i * 2048] = acc[qm][m][n][i];
      }
}

// ---------------- q post: RMSNorm + RoPE + Q_SCALE, bf16 -> bf16 ----------------
__global__ __launch_bounds__(256)
void k_qpost(const uint16_t* __restrict__ qg, const float* __restrict__ qs,
             uint16_t* __restrict__ qb) {
  int gw = blockIdx.x * 4 + (threadIdx.x >> 6);
  int lane = threadIdx.x & 63;
  int bt = gw / N_;
  int t = bt % T_;
  const uint16_t* src = qg + (long)gw * H_;
  float x1 = bf2f(src[lane]), x2 = bf2f(src[lane + 64]);
  float ssq = x1 * x1 + x2 * x2;
#pragma unroll
  for (int off = 1; off < 64; off <<= 1) ssq += __shfl_xor(ssq, off);
  float inv = rsqrtf(ssq * (1.0f / 128.0f) + 1e-6f);
  float n1 = x1 * inv * (1.0f + qs[lane]);
  float n2 = x2 * inv * (1.0f + qs[lane + 64]);
  float ts = powf(10000.0f, (float)lane * (2.0f / 128.0f));
  float ang = (float)t / ts;
  float sn, cs;
  sincosf(ang, &sn, &cs);
  const float QSC = 0.08838834764831845f;  // 128^-0.5
  uint16_t* dp = qb + (long)gw * H_;
  dp[lane] = f2bf((n1 * cs - n2 * sn) * QSC);
  dp[lane + 64] = f2bf((n2 * cs + n1 * sn) * QSC);
}

// ---------------- k post: RMSNorm + RoPE, bf16 in, (B,KH,T,H) pre-swizzled -------
__global__ __launch_bounds__(256)
void k_kpost(const uint16_t* __restrict__ kvg, const float* __restrict__ ks,
             uint16_t* __restrict__ kb) {
  int gw = blockIdx.x * 4 + (threadIdx.x >> 6);  // (b*T+t)*KH + kh
  int lane = threadIdx.x & 63;
  int kh = gw % KH_;
  int bt = gw / KH_;
  int t = bt % T_, b = bt / T_;
  const uint16_t* src = kvg + (long)bt * (KH_ * H_ * 2) + kh * H_;
  float x1 = bf2f(src[lane]), x2 = bf2f(src[lane + 64]);
  float ssq = x1 * x1 + x2 * x2;
#pragma unroll
  for (int off = 1; off < 64; off <<= 1) ssq += __shfl_xor(ssq, off);
  float inv = rsqrtf(ssq * (1.0f / 128.0f) + 1e-6f);
  float n1 = x1 * inv * (1.0f + ks[lane]);
  float n2 = x2 * inv * (1.0f + ks[lane + 64]);
  float ts = powf(10000.0f, (float)lane * (2.0f / 128.0f));
  float ang = (float)t / ts;
  float sn, cs;
  sincosf(ang, &sn, &cs);
  int sw = (t & 7) << 3;
  uint16_t* dp = kb + ((long)(b * KH_ + kh) * T_ + t) * H_;
  dp[lane ^ sw] = f2bf(n1 * cs - n2 * sn);
  dp[(lane + 64) ^ sw] = f2bf(n2 * cs + n1 * sn);
}

// ---------------- flash attention: fixed-max softmax, lean poly-tanh softcap ------
// (round-11 version: single-buffer gl_lds16 staging, 40KB LDS, 4 blocks/CU)
__global__ __launch_bounds__(256, 4)
void k_attn(const uint16_t* __restrict__ qb, const uint16_t* __restrict__ kb,
            const uint16_t* __restrict__ vbt, uint16_t* __restrict__ enc) {
  __shared__ uint16_t Ks[64 * 128];
  __shared__ uint16_t Vs[128 * 64];
  __shared__ uint16_t Pl[4][16 * 64];
  int tid = threadIdx.x, lane = tid & 63, w = tid >> 6;
  int nt = T_ / 64;
  int blk = blockIdx.x;
  int tq = nt - 1 - (blk >> 5);
  int bn = blk & 31;
  int n = bn % N_, b = bn / N_;
  int kh = n >> 1;  // G = 2
  int t0 = tq * 64;
  int tw = t0 + w * 16;
  int fr = lane & 15, fgrp = lane >> 4, fk = fgrp * 8;
  int sw3 = fr & 7;

  const uint16_t* qrow = qb + ((long)(b * T_ + tw + fr) * N_ + n) * H_;
  short8 aq[4];
#pragma unroll
  for (int kk = 0; kk < 4; ++kk) aq[kk] = *(const short8*)(qrow + kk * 32 + fk);

  float lrow[4];
  f32x4 o[8];
#pragma unroll
  for (int i = 0; i < 4; ++i) lrow[i] = 0.0f;
#pragma unroll
  for (int hf = 0; hf < 8; ++hf) o[hf] = (f32x4){0.f, 0.f, 0.f, 0.f};

  int s_begin = t0 - (WINDOW_ - 1);
  if (s_begin < 0) s_begin = 0;
  s_begin &= ~63;
  int s_endex = t0 + 64;

  const uint16_t* kbase = kb + (long)(b * KH_ + kh) * T_ * H_;
  const uint16_t* vbase = vbt + (long)(b * KH_ + kh) * H_ * T_;
  int krow_st = tid >> 4, kcol_st = (tid & 15) * 8;
  int vrow_st = tid >> 3, vcol_st = (tid & 7) * 8;
  char* ldsK = (char*)Ks + w * 1024;
  char* ldsV = (char*)Vs + w * 1024;
  uint16_t* Pw = Pl[w];

  for (int s0 = s_begin; s0 < s_endex; s0 += 64) {
    __syncthreads();
#pragma unroll
    for (int j = 0; j < 4; ++j) {
      gl_lds16(kbase + (long)(s0 + j * 16 + krow_st) * H_ + kcol_st, ldsK + j * 4096);
      gl_lds16(vbase + (long)(j * 32 + vrow_st) * T_ + s0 + vcol_st, ldsV + j * 4096);
    }
    __syncthreads();
    if (s0 > tw + 15 || s0 + 63 < tw - (WINDOW_ - 1)) continue;

    // ---- S = Q K^T ----
    f32x4 sc[4];
#pragma unroll
    for (int kc = 0; kc < 4; ++kc) {
      f32x4 a = (f32x4){0.f, 0.f, 0.f, 0.f};
      const uint16_t* kr = Ks + (kc * 16 + fr) * 128;
#pragma unroll
      for (int kk = 0; kk < 4; ++kk) {
        short8 bk = *(const short8*)(kr + ((((kk << 2) | fgrp) ^ sw3) << 3));
        a = __builtin_amdgcn_mfma_f32_16x16x32_bf16(aq[kk], bk, a, 0, 0, 0);
      }
      sc[kc] = a;
    }

    bool full = (s0 + 63 <= tw) && (s0 >= tw + 16 - WINDOW_);
#define SMBODY(FULL)                                                              \
    _Pragma("unroll") for (int i = 0; i < 4; ++i) {                               \
      int r = fgrp * 4 + i;                                                       \
      int rsw = (r & 7) << 3;                                                     \
      int trowq = tw + r;                                                         \
      float ps = 0.f;                                                             \
      _Pragma("unroll") for (int kc = 0; kc < 4; ++kc) {                          \
        float v = sc[kc][i];                                                      \
        float u = v * v * 4.0e-4f;                                                \
        float t50 = v * fmaf(u, fmaf(u, fmaf(u, -0.053968254f, 0.13333334f),      \
                                     -0.33333334f), 1.0f);                        \
        float p = __expf(t50 - 20.0f);                                            \
        if (!(FULL)) {                                                            \
          int s = s0 + kc * 16 + fr;                                              \
          bool ok = (s <= trowq) && (s > trowq - WINDOW_);                        \
          p = ok ? p : 0.0f;                                                      \
        }                                                                         \
        ps += p;                                                                  \
        *(__hip_bfloat16*)(Pw + r * 64 + ((kc * 16 + fr) ^ rsw)) =                \
            __float2bfloat16(p);                                                  \
      }                                                                           \
      lrow[i] += ps;                                                              \
    }
    if (full) { SMBODY(true) } else { SMBODY(false) }
#undef SMBODY

    // ---- O += P V ----
    short8 pa0 = *(const short8*)(Pw + fr * 64 + ((fgrp ^ sw3) << 3));
    short8 pa1 = *(const short8*)(Pw + fr * 64 + (((4 | fgrp) ^ sw3) << 3));
#pragma unroll
    for (int hf = 0; hf < 8; ++hf) {
      const uint16_t* vr = Vs + (hf * 16 + fr) * 64;
      short8 bv0 = *(const short8*)(vr + ((fgrp ^ sw3) << 3));
      short8 bv1 = *(const short8*)(vr + (((4 | fgrp) ^ sw3) << 3));
      o[hf] = __builtin_amdgcn_mfma_f32_16x16x32_bf16(pa0, bv0, o[hf], 0, 0, 0);
      o[hf] = __builtin_amdgcn_mfma_f32_16x16x32_bf16(pa1, bv1, o[hf], 0, 0, 0);
    }
  }

#pragma unroll
  for (int i = 0; i < 4; ++i) {
#pragma unroll
    for (int off = 1; off < 16; off <<= 1) lrow[i] += __shfl_xor(lrow[i], off);
    lrow[i] = 1.0f / lrow[i];
  }
#pragma unroll
  for (int hf = 0; hf < 8; ++hf)
#pragma unroll
    for (int i = 0; i < 4; ++i) {
      int t = tw + fgrp * 4 + i;
      float val = o[hf][i] * lrow[i];
      enc[((long)(b * T_ + t) * N_ + n) * H_ + hf * 16 + fr] = f2bf(val);
    }
}

// ---------------- host side ----------------
extern "C" void kernel_launch(void* const* d_in, const int* in_sizes, int n_in,
                              void* d_out, int out_size, void* d_ws, size_t ws_size,
                              hipStream_t stream) {
  const float* x = (const float*)d_in[0];
  const float* w_q = (const float*)d_in[1];
  const float* w_kv = (const float*)d_in[2];
  const float* w_o = (const float*)d_in[3];
  const float* qns = (const float*)d_in[4];
  const float* kns = (const float*)d_in[5];
  float* out = (float*)d_out;

  uint16_t* ws = (uint16_t*)d_ws;
  uint16_t* xb    = ws;                    // 8388608  : x bf16 (B*T, D)
  uint16_t* wq_t  = xb    + 8388608;       // 4194304  : (N*H, D)
  uint16_t* wkv_t = wq_t  + 4194304;       // 4194304  : contiguous after wq_t -> fused B panel
  uint16_t* wo_t  = wkv_t + 4194304;       // 4194304  : (D, N*H)
  uint16_t* qb    = wo_t  + 4194304;       // 8388608  : (B,T,N,H)
  uint16_t* kb    = qb    + 8388608;       // 4194304  : (B,KH,T,H) pre-swizzled
  uint16_t* vbt   = kb    + 4194304;       // 4194304  : (B,KH,H,T) pre-swizzled
  uint16_t* enc   = vbt   + 4194304;       // 8388608  : (B,T,N,H)
  uint16_t* qg_b  = enc   + 8388608;       // 8388608  : q gemm out bf16 (B*T, N*H)
  uint16_t* kvg_b = qg_b  + 8388608;       // 8388608  : kv gemm out bf16 (B*T, 2*KH*H)
  if (ws_size < (size_t)125829120) return;

  dim3 tb(32, 8);
  k_f2b4<<<8192, 256, 0, stream>>>(x, xb, 8388608);
  k_prep_qkv<<<dim3(4, 64, 32), tb, 0, stream>>>(w_q, w_kv, wq_t, wkv_t);
  k_transpose_f2b<<<dim3(64, 64, 1), tb, 0, stream>>>(w_o, wo_t, 2048, 2048, 1,
      0, 0, 0, 0, 2048);
  // fused q+kv projection, bf16 out: cols<2048 -> qg_b, else kvg_b
  k_gemm8<<<256, 512, 0, stream>>>(xb, wq_t, qg_b, kvg_b, 16, 2048);
  k_qpost<<<(B_ * T_ * N_) / 4, 256, 0, stream>>>(qg_b, qns, qb);
  k_kpost<<<(B_ * T_ * KH_) / 4, 256, 0, stream>>>(kvg_b, kns, kb);
  k_transpose_v<<<dim3(4, 64, 16), tb, 0, stream>>>(kvg_b, vbt);
  k_attn<<<B_ * N_ * (T_ / 64), 256, 0, stream>>>(qb, kb, vbt, enc);
  // output projection: 256x128 tiles -> 256 blocks (full chip)
  k_gemm8n<<<256, 512, 0, stream>>>(enc, wo_t, out, 16);
}